// Round 10
// baseline (232.786 us; speedup 1.0000x reference)
//
#include <hip/hip_runtime.h>
#include <hip/hip_bf16.h>

#define N_NODES 100000
#define N_EDGES 1600000
#define D 32
#define N_GRAPHS 128

#define WIN 128                                   // nodes per dst window
#define NWINS ((N_NODES + WIN - 1) / WIN)         // 782
#define CAP 2560                                  // bucket capacity (mean 2046)
#define NPW 2                                     // nodes per wave
#define IDXCAP 128                                // staged indices per wave (mean 32, +17 sd)

// ---- Stage 1: bin edges by 128-node dst window, coalesced bucket writes ----
__global__ void bin_kernel(const int* __restrict__ src,
                           const int* __restrict__ dst,
                           int* __restrict__ gfill,
                           int* __restrict__ ebuf) {
    __shared__ int lhist[NWINS];
    __shared__ int lbase[NWINS];
    const int tid = threadIdx.x;
    const int per = (N_EDGES + gridDim.x - 1) / gridDim.x;
    const int e0 = blockIdx.x * per;
    const int e1 = (e0 + per < N_EDGES) ? e0 + per : N_EDGES;

    for (int b = tid; b < NWINS; b += blockDim.x) lhist[b] = 0;
    __syncthreads();
    for (int e = e0 + tid; e < e1; e += blockDim.x)
        atomicAdd(&lhist[dst[e] >> 7], 1);
    __syncthreads();
    for (int b = tid; b < NWINS; b += blockDim.x) {
        int c = lhist[b];
        lbase[b] = c ? atomicAdd(&gfill[b], c) : 0;
        lhist[b] = 0;
    }
    __syncthreads();
    for (int e = e0 + tid; e < e1; e += blockDim.x) {
        int d = dst[e];
        int bn = d >> 7;
        int r = atomicAdd(&lhist[bn], 1);
        int off = lbase[bn] + r;
        if (off < CAP) ebuf[bn * CAP + off] = ((d & (WIN - 1)) << 17) | src[e];
    }
}

// ---- Stage 2: exclusive scan of window counts ----
__global__ void wscan_kernel(const int* __restrict__ gfill, int* __restrict__ wbase) {
    __shared__ int s[1024];
    const int t = threadIdx.x;
    int v = (t < NWINS) ? gfill[t] : 0;
    s[t] = v;
    __syncthreads();
    for (int off = 1; off < 1024; off <<= 1) {
        int a = (t >= off) ? s[t - off] : 0;
        __syncthreads();
        s[t] += a;
        __syncthreads();
    }
    if (t < NWINS) wbase[t] = s[t] - v;
    if (t == NWINS - 1) wbase[NWINS] = s[t];
}

// ---- Stage 3: per-window LDS-local sort -> dst-sorted CSR, coalesced out ----
__global__ void csr_local_kernel(const int* __restrict__ ebuf,
                                 const int* __restrict__ wbase,
                                 int* __restrict__ esrc,
                                 int* __restrict__ rend,
                                 int* __restrict__ deg) {
    __shared__ int pk[CAP];
    __shared__ int ssrc[CAP];
    __shared__ int hs[WIN];
    __shared__ int hcnt[WIN];
    __shared__ int cur[WIN];
    const int tid = threadIdx.x;
    const int w = blockIdx.x;
    const int base_out = wbase[w];
    int cnt = wbase[w + 1] - base_out;
    if (cnt > CAP) cnt = CAP;
    const int n0 = w * WIN;

    for (int i = tid; i < cnt; i += 256) pk[i] = ebuf[w * CAP + i];
    if (tid < WIN) hcnt[tid] = 0;
    __syncthreads();
    for (int i = tid; i < cnt; i += 256) atomicAdd(&hcnt[pk[i] >> 17], 1);
    __syncthreads();
    if (tid < WIN) hs[tid] = hcnt[tid];
    __syncthreads();
    for (int off = 1; off < WIN; off <<= 1) {
        int a = 0;
        if (tid < WIN && tid >= off) a = hs[tid - off];
        __syncthreads();
        if (tid < WIN) hs[tid] += a;
        __syncthreads();
    }
    if (tid < WIN) {
        const int incl = hs[tid];
        const int c = hcnt[tid];
        cur[tid] = incl - c;
        const int n = n0 + tid;
        if (n < N_NODES) { rend[n] = base_out + incl; deg[n] = c; }
    }
    __syncthreads();
    for (int i = tid; i < cnt; i += 256) {
        const int p = pk[i];
        const int pos = atomicAdd(&cur[p >> 17], 1);
        ssrc[pos] = p & 0x1FFFF;
    }
    __syncthreads();
    for (int i = tid; i < cnt; i += 256) esrc[base_out + i] = ssrc[i];
}

// ---- Fused GIN layer: 2 nodes/wave, LDS-staged indices, 4 independent
// gathers per iteration (32 edges in flight/wave), f32 throughout.
// Lane = (g = lane>>5, es = (lane>>3)&3, fq = lane&7). Phase A: gather+
// accumulate; es-reduce; stage rows to LDS. Phase B: lane = (ig = lane>>3,
// og = lane&7) register-fragment matvec + ReLU / pool. Explicit barriers
// between LDS write/read phases (no same-wave-ordering assumptions).
template <bool RELU, bool POOL>
__global__ void __launch_bounds__(256)
gin_layer_kernel(const float* __restrict__ x,
                 const int* __restrict__ esrc,
                 const int* __restrict__ rend,
                 const int* __restrict__ deg,
                 const float* __restrict__ W,
                 const float* __restrict__ bias,
                 const int* __restrict__ graph_ids,
                 float* __restrict__ out) {
    __shared__ int   lidx[4][IDXCAP];
    __shared__ float lagg[4][NPW * D];
    const int lane = threadIdx.x & 63;
    const int wslot = threadIdx.x >> 6;
    const int g  = lane >> 5;          // node within wave (0..1)  [bit 5]
    const int es = (lane >> 3) & 3;    // edge slot (0..3)         [bits 4:3]
    const int fq = lane & 7;           // float-quad (0..7)        [bits 2:0]

    // Phase-B fragment: lane = (ig, og)
    const int og = lane & 7;
    const int ig = lane >> 3;
    float w[4][4];
#pragma unroll
    for (int k = 0; k < 4; ++k) {
        const float4 t = *reinterpret_cast<const float4*>(&W[(ig * 4 + k) * D + og * 4]);
        w[k][0] = t.x; w[k][1] = t.y; w[k][2] = t.z; w[k][3] = t.w;
    }
    const float4 bv = *reinterpret_cast<const float4*>(&bias[og * 4]);

    const int wid = blockIdx.x * 4 + wslot;          // 50000 waves exactly
    const int v0 = wid * NPW;
    const int vg = v0 + g;
    const int dg = deg[vg];
    const int sg = rend[vg] - dg;                    // row start of node vg
    const int S = __shfl(sg, 0);                     // wave range start (g=0 row)
    const int offg = sg - S;                         // node's offset in range

    // stage the wave's contiguous index range [S, S+128) into LDS
    int t0 = S + lane;      if (t0 > N_EDGES - 1) t0 = N_EDGES - 1;
    int t1 = S + 64 + lane; if (t1 > N_EDGES - 1) t1 = N_EDGES - 1;
    lidx[wslot][lane] = esrc[t0];
    lidx[wslot][64 + lane] = esrc[t1];
    __syncthreads();   // all waves staged (removes same-wave LDS-order reliance)

    int Jn = (dg + 3) >> 2;                          // 4-edge chunks this node
    int Jmax = Jn;
    { int t = __shfl_xor(Jmax, 32); Jmax = Jmax > t ? Jmax : t; }

    float a0 = 0.f, a1 = 0.f, a2 = 0.f, a3 = 0.f;
    if (es == 0) {   // self term (eps = 0), once per (g, fq)
        const float4 sv = *reinterpret_cast<const float4*>(&x[(size_t)vg * D + fq * 4]);
        a0 = sv.x; a1 = sv.y; a2 = sv.z; a3 = sv.w;
    }

    for (int c = 0; c < Jmax; c += 4) {
        const int e0 = (c + 0) * 4 + es; const bool b0 = e0 < dg; const int o0 = offg + e0;
        const int e1 = (c + 1) * 4 + es; const bool b1 = e1 < dg; const int o1 = offg + e1;
        const int e2 = (c + 2) * 4 + es; const bool b2 = e2 < dg; const int o2 = offg + e2;
        const int e3 = (c + 3) * 4 + es; const bool b3 = e3 < dg; const int o3 = offg + e3;

        int p0 = lidx[wslot][o0 < IDXCAP ? o0 : 0];
        int p1 = lidx[wslot][o1 < IDXCAP ? o1 : 0];
        int p2 = lidx[wslot][o2 < IDXCAP ? o2 : 0];
        int p3 = lidx[wslot][o3 < IDXCAP ? o3 : 0];
        if (b0 && o0 >= IDXCAP) p0 = esrc[S + o0];   // ~never taken
        if (b1 && o1 >= IDXCAP) p1 = esrc[S + o1];
        if (b2 && o2 >= IDXCAP) p2 = esrc[S + o2];
        if (b3 && o3 >= IDXCAP) p3 = esrc[S + o3];

        // 4 mutually independent row gathers (8 rows per instr across wave)
        if (b0) { const float4 G = *reinterpret_cast<const float4*>(&x[(size_t)p0 * D + fq * 4]);
                  a0 += G.x; a1 += G.y; a2 += G.z; a3 += G.w; }
        if (b1) { const float4 G = *reinterpret_cast<const float4*>(&x[(size_t)p1 * D + fq * 4]);
                  a0 += G.x; a1 += G.y; a2 += G.z; a3 += G.w; }
        if (b2) { const float4 G = *reinterpret_cast<const float4*>(&x[(size_t)p2 * D + fq * 4]);
                  a0 += G.x; a1 += G.y; a2 += G.z; a3 += G.w; }
        if (b3) { const float4 G = *reinterpret_cast<const float4*>(&x[(size_t)p3 * D + fq * 4]);
                  a0 += G.x; a1 += G.y; a2 += G.z; a3 += G.w; }
    }

    // reduce over the 4 edge-slots (lane bits 3,4)
    a0 += __shfl_xor(a0, 8);  a1 += __shfl_xor(a1, 8);
    a2 += __shfl_xor(a2, 8);  a3 += __shfl_xor(a3, 8);
    a0 += __shfl_xor(a0, 16); a1 += __shfl_xor(a1, 16);
    a2 += __shfl_xor(a2, 16); a3 += __shfl_xor(a3, 16);

    if (es == 0) {
        float4 o; o.x = a0; o.y = a1; o.z = a2; o.w = a3;
        *reinterpret_cast<float4*>(&lagg[wslot][g * D + fq * 4]) = o;
    }
    __syncthreads();   // aggregated rows visible

    // ---- Phase B: matvec + epilogue for the wave's 2 nodes ----
    float pl0 = 0.f, pl1 = 0.f, pl2 = 0.f, pl3 = 0.f;
    int cur_g = POOL ? graph_ids[v0] : 0;
#pragma unroll
    for (int n = 0; n < NPW; ++n) {
        const int v = v0 + n;
        const float4 q = *reinterpret_cast<const float4*>(&lagg[wslot][n * D + ig * 4]);
        float y0 = q.x * w[0][0] + q.y * w[1][0] + q.z * w[2][0] + q.w * w[3][0];
        float y1 = q.x * w[0][1] + q.y * w[1][1] + q.z * w[2][1] + q.w * w[3][1];
        float y2 = q.x * w[0][2] + q.y * w[1][2] + q.z * w[2][2] + q.w * w[3][2];
        float y3 = q.x * w[0][3] + q.y * w[1][3] + q.z * w[2][3] + q.w * w[3][3];
        y0 += __shfl_xor(y0, 8);  y1 += __shfl_xor(y1, 8);
        y2 += __shfl_xor(y2, 8);  y3 += __shfl_xor(y3, 8);
        y0 += __shfl_xor(y0, 16); y1 += __shfl_xor(y1, 16);
        y2 += __shfl_xor(y2, 16); y3 += __shfl_xor(y3, 16);
        y0 += __shfl_xor(y0, 32); y1 += __shfl_xor(y1, 32);
        y2 += __shfl_xor(y2, 32); y3 += __shfl_xor(y3, 32);
        y0 += bv.x; y1 += bv.y; y2 += bv.z; y3 += bv.w;
        if (RELU) {
            y0 = fmaxf(y0, 0.f); y1 = fmaxf(y1, 0.f);
            y2 = fmaxf(y2, 0.f); y3 = fmaxf(y3, 0.f);
        }
        if (POOL) {
            const int gg = graph_ids[v];
            if (gg != cur_g) {
                if (ig == 0) {
                    atomicAdd(&out[cur_g * D + og * 4 + 0], pl0);
                    atomicAdd(&out[cur_g * D + og * 4 + 1], pl1);
                    atomicAdd(&out[cur_g * D + og * 4 + 2], pl2);
                    atomicAdd(&out[cur_g * D + og * 4 + 3], pl3);
                }
                pl0 = pl1 = pl2 = pl3 = 0.f;
                cur_g = gg;
            }
            pl0 += y0; pl1 += y1; pl2 += y2; pl3 += y3;
        } else if (ig == 0) {
            float4 o; o.x = y0; o.y = y1; o.z = y2; o.w = y3;
            *reinterpret_cast<float4*>(&out[(size_t)v * D + og * 4]) = o;
        }
    }
    if (POOL && ig == 0) {
        atomicAdd(&out[cur_g * D + og * 4 + 0], pl0);
        atomicAdd(&out[cur_g * D + og * 4 + 1], pl1);
        atomicAdd(&out[cur_g * D + og * 4 + 2], pl2);
        atomicAdd(&out[cur_g * D + og * 4 + 3], pl3);
    }
}

extern "C" void kernel_launch(void* const* d_in, const int* in_sizes, int n_in,
                              void* d_out, int out_size, void* d_ws, size_t ws_size,
                              hipStream_t stream) {
    const float* feats = (const float*)d_in[0];
    const int* src = (const int*)d_in[1];
    const int* dst = (const int*)d_in[2];
    const int* graph_ids = (const int*)d_in[3];
    const float* W1 = (const float*)d_in[4];
    const float* b1 = (const float*)d_in[5];
    const float* W2 = (const float*)d_in[6];
    const float* b2 = (const float*)d_in[7];
    float* out = (float*)d_out;

    int* gfill = (int*)d_ws;                               // 1024
    int* wbase = gfill + 1024;                             // 1024 (NWINS+1)
    int* ebuf  = wbase + 1024;                             // NWINS*CAP (~8 MB)
    int* esrc  = ebuf + (size_t)NWINS * CAP;               // N_EDGES
    int* rend  = esrc + N_EDGES;                           // N_NODES
    int* deg   = rend + N_NODES;                           // N_NODES
    float* h   = (float*)(deg + N_NODES);                  // N_NODES*D f32

    const int total_waves = (N_NODES + NPW - 1) / NPW;     // 50000
    const int layer_blocks = (total_waves + 3) / 4;        // 12500

    // ---- Build dst-sorted CSR via window binning + LDS-local sort ----
    hipMemsetAsync(gfill, 0, 1024 * sizeof(int), stream);
    bin_kernel<<<256, 512, 0, stream>>>(src, dst, gfill, ebuf);
    wscan_kernel<<<1, 1024, 0, stream>>>(gfill, wbase);
    csr_local_kernel<<<NWINS, 256, 0, stream>>>(ebuf, wbase, esrc, rend, deg);

    // ---- Layer 1: h = relu((x + agg(x)) @ W1 + b1) ----
    gin_layer_kernel<true, false><<<layer_blocks, 256, 0, stream>>>(
        feats, esrc, rend, deg, W1, b1, graph_ids, h);

    // ---- Layer 2 + sum pooling ----
    hipMemsetAsync(out, 0, (size_t)out_size * sizeof(float), stream);
    gin_layer_kernel<false, true><<<layer_blocks, 256, 0, stream>>>(
        h, esrc, rend, deg, W2, b2, graph_ids, out);
}

// Round 11
// 200.133 us; speedup vs baseline: 1.1632x; 1.1632x over previous
//
#include <hip/hip_runtime.h>
#include <hip/hip_bf16.h>

#define N_NODES 100000
#define N_EDGES 1600000
#define D 32
#define N_GRAPHS 128

#define WIN 128                                   // nodes per dst window
#define NWINS ((N_NODES + WIN - 1) / WIN)         // 782
#define CAP 2560                                  // bucket capacity (mean 2046)
#define NPW 8                                     // nodes per wave (100000 = 12500 waves exactly)

// ---- Stage 1: bin edges by 128-node dst window, coalesced bucket writes ----
__global__ void bin_kernel(const int* __restrict__ src,
                           const int* __restrict__ dst,
                           int* __restrict__ gfill,
                           int* __restrict__ ebuf) {
    __shared__ int lhist[NWINS];
    __shared__ int lbase[NWINS];
    const int tid = threadIdx.x;
    const int per = (N_EDGES + gridDim.x - 1) / gridDim.x;
    const int e0 = blockIdx.x * per;
    const int e1 = (e0 + per < N_EDGES) ? e0 + per : N_EDGES;

    for (int b = tid; b < NWINS; b += blockDim.x) lhist[b] = 0;
    __syncthreads();
    for (int e = e0 + tid; e < e1; e += blockDim.x)
        atomicAdd(&lhist[dst[e] >> 7], 1);
    __syncthreads();
    for (int b = tid; b < NWINS; b += blockDim.x) {
        int c = lhist[b];
        lbase[b] = c ? atomicAdd(&gfill[b], c) : 0;
        lhist[b] = 0;
    }
    __syncthreads();
    for (int e = e0 + tid; e < e1; e += blockDim.x) {
        int d = dst[e];
        int bn = d >> 7;
        int r = atomicAdd(&lhist[bn], 1);
        int off = lbase[bn] + r;
        if (off < CAP) ebuf[bn * CAP + off] = ((d & (WIN - 1)) << 17) | src[e];
    }
}

// ---- Stage 2: exclusive scan of window counts ----
__global__ void wscan_kernel(const int* __restrict__ gfill, int* __restrict__ wbase) {
    __shared__ int s[1024];
    const int t = threadIdx.x;
    int v = (t < NWINS) ? gfill[t] : 0;
    s[t] = v;
    __syncthreads();
    for (int off = 1; off < 1024; off <<= 1) {
        int a = (t >= off) ? s[t - off] : 0;
        __syncthreads();
        s[t] += a;
        __syncthreads();
    }
    if (t < NWINS) wbase[t] = s[t] - v;
    if (t == NWINS - 1) wbase[NWINS] = s[t];
}

// ---- Stage 3: per-window LDS-local sort -> dst-sorted CSR, coalesced out ----
__global__ void csr_local_kernel(const int* __restrict__ ebuf,
                                 const int* __restrict__ wbase,
                                 int* __restrict__ esrc,
                                 int* __restrict__ rend,
                                 int* __restrict__ deg) {
    __shared__ int pk[CAP];
    __shared__ int ssrc[CAP];
    __shared__ int hs[WIN];
    __shared__ int hcnt[WIN];
    __shared__ int cur[WIN];
    const int tid = threadIdx.x;
    const int w = blockIdx.x;
    const int base_out = wbase[w];
    int cnt = wbase[w + 1] - base_out;
    if (cnt > CAP) cnt = CAP;
    const int n0 = w * WIN;

    for (int i = tid; i < cnt; i += 256) pk[i] = ebuf[w * CAP + i];
    if (tid < WIN) hcnt[tid] = 0;
    __syncthreads();
    for (int i = tid; i < cnt; i += 256) atomicAdd(&hcnt[pk[i] >> 17], 1);
    __syncthreads();
    if (tid < WIN) hs[tid] = hcnt[tid];
    __syncthreads();
    for (int off = 1; off < WIN; off <<= 1) {
        int a = 0;
        if (tid < WIN && tid >= off) a = hs[tid - off];
        __syncthreads();
        if (tid < WIN) hs[tid] += a;
        __syncthreads();
    }
    if (tid < WIN) {
        const int incl = hs[tid];
        const int c = hcnt[tid];
        cur[tid] = incl - c;
        const int n = n0 + tid;
        if (n < N_NODES) { rend[n] = base_out + incl; deg[n] = c; }
    }
    __syncthreads();
    for (int i = tid; i < cnt; i += 256) {
        const int p = pk[i];
        const int pos = atomicAdd(&cur[p >> 17], 1);
        ssrc[pos] = p & 0x1FFFF;
    }
    __syncthreads();
    for (int i = tid; i < cnt; i += 256) esrc[base_out + i] = ssrc[i];
}

// ---- Fused GIN layer: round-7 structure + BATCHED phase A ----
// Wave = 8 edge-slots (es) x 8 feature-quads (fq), 8 nodes/wave. Change vs
// round 7: the first 16 edges of ALL 8 nodes are gathered as independent
// straight-line code (16 gathers in flight vs 2), with per-node metadata
// (rend/deg/graph_ids) fetched by ONE coalesced load each and the 8 self
// rows fetched by ONE instruction. Tails (deg>16, ~10% of edges) and the
// proven reduce/matvec/pool epilogue are identical to round 7.
template <bool RELU, bool POOL>
__global__ void __launch_bounds__(256)
gin_layer_kernel(const float* __restrict__ x,
                 const int* __restrict__ esrc,
                 const int* __restrict__ rend,
                 const int* __restrict__ deg,
                 const float* __restrict__ W,
                 const float* __restrict__ bias,
                 const int* __restrict__ graph_ids,
                 float* __restrict__ out) {
    const int lane = threadIdx.x & 63;
    const int es = lane >> 3;
    const int fq = lane & 7;

    float w[4][4];
#pragma unroll
    for (int k = 0; k < 4; ++k) {
        const float4 t = *reinterpret_cast<const float4*>(&W[(es * 4 + k) * D + fq * 4]);
        w[k][0] = t.x; w[k][1] = t.y; w[k][2] = t.z; w[k][3] = t.w;
    }
    const float4 bv = *reinterpret_cast<const float4*>(&bias[fq * 4]);

    const int wid = blockIdx.x * 4 + (threadIdx.x >> 6);   // 12500 waves exactly
    const int v0 = wid * NPW;

    // batched per-node metadata: lane&7 indexes the node (coalesced loads)
    const int vv = v0 + (lane & 7);
    const int rend_v = rend[vv];
    const int deg_v = deg[vv];
    const int gid_v = POOL ? graph_ids[vv] : 0;

    // all 8 self rows in ONE instruction: es-group e loads node v0+e's row
    const float4 sv = *reinterpret_cast<const float4*>(&x[(size_t)(v0 + es) * D + fq * 4]);

    float acc[8][4];
#pragma unroll
    for (int n = 0; n < 8; ++n) { acc[n][0] = 0.f; acc[n][1] = 0.f; acc[n][2] = 0.f; acc[n][3] = 0.f; }
#pragma unroll
    for (int n = 0; n < 8; ++n) {
        if (es == n) { acc[n][0] += sv.x; acc[n][1] += sv.y; acc[n][2] += sv.z; acc[n][3] += sv.w; }
    }

    int Dn[8], Sn[8];
#pragma unroll
    for (int n = 0; n < 8; ++n) {
        Dn[n] = __shfl(deg_v, n);
        Sn[n] = __shfl(rend_v, n) - Dn[n];
    }

    // ---- batched first-16-edges: 16 independent index loads, then 16
    // independent gathers (per-lane exec-masked; masked lanes don't access
    // memory, so no OOB and no wasted lines) ----
    int idx0[8], idx1[8];
#pragma unroll
    for (int n = 0; n < 8; ++n) {
        idx0[n] = (es < Dn[n]) ? esrc[Sn[n] + es] : -1;
        idx1[n] = (8 + es < Dn[n]) ? esrc[Sn[n] + 8 + es] : -1;
    }
#pragma unroll
    for (int n = 0; n < 8; ++n) {
        if (idx0[n] >= 0) {
            const float4 G = *reinterpret_cast<const float4*>(&x[(size_t)idx0[n] * D + fq * 4]);
            acc[n][0] += G.x; acc[n][1] += G.y; acc[n][2] += G.z; acc[n][3] += G.w;
        }
        if (idx1[n] >= 0) {
            const float4 G = *reinterpret_cast<const float4*>(&x[(size_t)idx1[n] * D + fq * 4]);
            acc[n][0] += G.x; acc[n][1] += G.y; acc[n][2] += G.z; acc[n][3] += G.w;
        }
    }

    // ---- tails: edges 16..deg (Poisson(16) -> ~10% of edges) ----
#pragma unroll
    for (int n = 0; n < 8; ++n) {
        const int Rn = Sn[n] + Dn[n];
        for (int e = Sn[n] + 16; e < Rn; e += 8) {
            const int r = e + es;
            if (r < Rn) {
                const int s0 = esrc[r];
                const float4 G = *reinterpret_cast<const float4*>(&x[(size_t)s0 * D + fq * 4]);
                acc[n][0] += G.x; acc[n][1] += G.y; acc[n][2] += G.z; acc[n][3] += G.w;
            }
        }
    }

    // ---- epilogue per node (identical math to round 7) ----
    float pl0 = 0.f, pl1 = 0.f, pl2 = 0.f, pl3 = 0.f;
    int cur_g = POOL ? __shfl(gid_v, 0) : 0;
#pragma unroll
    for (int n = 0; n < 8; ++n) {
        float a0 = acc[n][0], a1 = acc[n][1], a2 = acc[n][2], a3 = acc[n][3];
        a0 += __shfl_xor(a0, 8);  a1 += __shfl_xor(a1, 8);  a2 += __shfl_xor(a2, 8);  a3 += __shfl_xor(a3, 8);
        a0 += __shfl_xor(a0, 16); a1 += __shfl_xor(a1, 16); a2 += __shfl_xor(a2, 16); a3 += __shfl_xor(a3, 16);
        a0 += __shfl_xor(a0, 32); a1 += __shfl_xor(a1, 32); a2 += __shfl_xor(a2, 32); a3 += __shfl_xor(a3, 32);

        const float q0 = __shfl(a0, es, 8);
        const float q1 = __shfl(a1, es, 8);
        const float q2 = __shfl(a2, es, 8);
        const float q3 = __shfl(a3, es, 8);

        float y0 = q0 * w[0][0] + q1 * w[1][0] + q2 * w[2][0] + q3 * w[3][0];
        float y1 = q0 * w[0][1] + q1 * w[1][1] + q2 * w[2][1] + q3 * w[3][1];
        float y2 = q0 * w[0][2] + q1 * w[1][2] + q2 * w[2][2] + q3 * w[3][2];
        float y3 = q0 * w[0][3] + q1 * w[1][3] + q2 * w[2][3] + q3 * w[3][3];

        y0 += __shfl_xor(y0, 8);  y1 += __shfl_xor(y1, 8);  y2 += __shfl_xor(y2, 8);  y3 += __shfl_xor(y3, 8);
        y0 += __shfl_xor(y0, 16); y1 += __shfl_xor(y1, 16); y2 += __shfl_xor(y2, 16); y3 += __shfl_xor(y3, 16);
        y0 += __shfl_xor(y0, 32); y1 += __shfl_xor(y1, 32); y2 += __shfl_xor(y2, 32); y3 += __shfl_xor(y3, 32);

        y0 += bv.x; y1 += bv.y; y2 += bv.z; y3 += bv.w;
        if (RELU) {
            y0 = fmaxf(y0, 0.f); y1 = fmaxf(y1, 0.f); y2 = fmaxf(y2, 0.f); y3 = fmaxf(y3, 0.f);
        }

        if (POOL) {
            const int gg = __shfl(gid_v, n);
            if (gg != cur_g) {
                if (es == 0) {
                    atomicAdd(&out[cur_g * D + fq * 4 + 0], pl0);
                    atomicAdd(&out[cur_g * D + fq * 4 + 1], pl1);
                    atomicAdd(&out[cur_g * D + fq * 4 + 2], pl2);
                    atomicAdd(&out[cur_g * D + fq * 4 + 3], pl3);
                }
                pl0 = pl1 = pl2 = pl3 = 0.f;
                cur_g = gg;
            }
            pl0 += y0; pl1 += y1; pl2 += y2; pl3 += y3;
        } else if (es == 0) {
            float4 o; o.x = y0; o.y = y1; o.z = y2; o.w = y3;
            *reinterpret_cast<float4*>(&out[(size_t)(v0 + n) * D + fq * 4]) = o;
        }
    }
    if (POOL && es == 0) {
        atomicAdd(&out[cur_g * D + fq * 4 + 0], pl0);
        atomicAdd(&out[cur_g * D + fq * 4 + 1], pl1);
        atomicAdd(&out[cur_g * D + fq * 4 + 2], pl2);
        atomicAdd(&out[cur_g * D + fq * 4 + 3], pl3);
    }
}

extern "C" void kernel_launch(void* const* d_in, const int* in_sizes, int n_in,
                              void* d_out, int out_size, void* d_ws, size_t ws_size,
                              hipStream_t stream) {
    const float* feats = (const float*)d_in[0];
    const int* src = (const int*)d_in[1];
    const int* dst = (const int*)d_in[2];
    const int* graph_ids = (const int*)d_in[3];
    const float* W1 = (const float*)d_in[4];
    const float* b1 = (const float*)d_in[5];
    const float* W2 = (const float*)d_in[6];
    const float* b2 = (const float*)d_in[7];
    float* out = (float*)d_out;

    int* gfill = (int*)d_ws;                               // 1024
    int* wbase = gfill + 1024;                             // 1024 (NWINS+1)
    int* ebuf  = wbase + 1024;                             // NWINS*CAP (~8 MB)
    int* esrc  = ebuf + (size_t)NWINS * CAP;               // N_EDGES
    int* rend  = esrc + N_EDGES;                           // N_NODES
    int* deg   = rend + N_NODES;                           // N_NODES
    float* h   = (float*)(deg + N_NODES);                  // N_NODES*D f32

    const int total_waves = N_NODES / NPW;                 // 12500 exactly
    const int layer_blocks = total_waves / 4;              // 3125

    // ---- Build dst-sorted CSR via window binning + LDS-local sort ----
    hipMemsetAsync(gfill, 0, 1024 * sizeof(int), stream);
    bin_kernel<<<256, 512, 0, stream>>>(src, dst, gfill, ebuf);
    wscan_kernel<<<1, 1024, 0, stream>>>(gfill, wbase);
    csr_local_kernel<<<NWINS, 256, 0, stream>>>(ebuf, wbase, esrc, rend, deg);

    // ---- Layer 1: h = relu((x + agg(x)) @ W1 + b1) ----
    gin_layer_kernel<true, false><<<layer_blocks, 256, 0, stream>>>(
        feats, esrc, rend, deg, W1, b1, graph_ids, h);

    // ---- Layer 2 + sum pooling ----
    hipMemsetAsync(out, 0, (size_t)out_size * sizeof(float), stream);
    gin_layer_kernel<false, true><<<layer_blocks, 256, 0, stream>>>(
        h, esrc, rend, deg, W2, b2, graph_ids, out);
}

// Round 12
// 145.320 us; speedup vs baseline: 1.6019x; 1.3772x over previous
//
#include <hip/hip_runtime.h>
#include <hip/hip_bf16.h>
#include <hip/hip_fp16.h>

#define N_NODES 100000
#define N_EDGES 1600000
#define D 32
#define N_GRAPHS 128

#define WIN 128                                   // nodes per dst window
#define NWINS ((N_NODES + WIN - 1) / WIN)         // 782
#define CAP 2560                                  // bucket capacity (mean 2046)
#define NODES_PER_WAVE 8

// ---- Stage 1: bin edges by 128-node dst window, coalesced bucket writes ----
__global__ void bin_kernel(const int* __restrict__ src,
                           const int* __restrict__ dst,
                           int* __restrict__ gfill,
                           int* __restrict__ ebuf) {
    __shared__ int lhist[NWINS];
    __shared__ int lbase[NWINS];
    const int tid = threadIdx.x;
    const int per = (N_EDGES + gridDim.x - 1) / gridDim.x;
    const int e0 = blockIdx.x * per;
    const int e1 = (e0 + per < N_EDGES) ? e0 + per : N_EDGES;

    for (int b = tid; b < NWINS; b += blockDim.x) lhist[b] = 0;
    __syncthreads();
    for (int e = e0 + tid; e < e1; e += blockDim.x)
        atomicAdd(&lhist[dst[e] >> 7], 1);
    __syncthreads();
    for (int b = tid; b < NWINS; b += blockDim.x) {
        int c = lhist[b];
        lbase[b] = c ? atomicAdd(&gfill[b], c) : 0;
        lhist[b] = 0;
    }
    __syncthreads();
    for (int e = e0 + tid; e < e1; e += blockDim.x) {
        int d = dst[e];
        int bn = d >> 7;
        int r = atomicAdd(&lhist[bn], 1);
        int off = lbase[bn] + r;
        if (off < CAP) ebuf[bn * CAP + off] = ((d & (WIN - 1)) << 17) | src[e];
    }
}

// ---- Stage 2: exclusive scan of window counts ----
__global__ void wscan_kernel(const int* __restrict__ gfill, int* __restrict__ wbase) {
    __shared__ int s[1024];
    const int t = threadIdx.x;
    int v = (t < NWINS) ? gfill[t] : 0;
    s[t] = v;
    __syncthreads();
    for (int off = 1; off < 1024; off <<= 1) {
        int a = (t >= off) ? s[t - off] : 0;
        __syncthreads();
        s[t] += a;
        __syncthreads();
    }
    if (t < NWINS) wbase[t] = s[t] - v;
    if (t == NWINS - 1) wbase[NWINS] = s[t];
}

// ---- Stage 3: per-window LDS-local sort -> dst-sorted CSR, coalesced out ----
__global__ void csr_local_kernel(const int* __restrict__ ebuf,
                                 const int* __restrict__ wbase,
                                 int* __restrict__ esrc,
                                 int* __restrict__ rend,
                                 int* __restrict__ deg) {
    __shared__ int pk[CAP];
    __shared__ int ssrc[CAP];
    __shared__ int hs[WIN];
    __shared__ int hcnt[WIN];
    __shared__ int cur[WIN];
    const int tid = threadIdx.x;
    const int w = blockIdx.x;
    const int base_out = wbase[w];
    int cnt = wbase[w + 1] - base_out;
    if (cnt > CAP) cnt = CAP;
    const int n0 = w * WIN;

    for (int i = tid; i < cnt; i += 256) pk[i] = ebuf[w * CAP + i];
    if (tid < WIN) hcnt[tid] = 0;
    __syncthreads();
    for (int i = tid; i < cnt; i += 256) atomicAdd(&hcnt[pk[i] >> 17], 1);
    __syncthreads();
    if (tid < WIN) hs[tid] = hcnt[tid];
    __syncthreads();
    for (int off = 1; off < WIN; off <<= 1) {
        int a = 0;
        if (tid < WIN && tid >= off) a = hs[tid - off];
        __syncthreads();
        if (tid < WIN) hs[tid] += a;
        __syncthreads();
    }
    if (tid < WIN) {
        const int incl = hs[tid];
        const int c = hcnt[tid];
        cur[tid] = incl - c;
        const int n = n0 + tid;
        if (n < N_NODES) { rend[n] = base_out + incl; deg[n] = c; }
    }
    __syncthreads();
    for (int i = tid; i < cnt; i += 256) {
        const int p = pk[i];
        const int pos = atomicAdd(&cur[p >> 17], 1);
        ssrc[pos] = p & 0x1FFFF;
    }
    __syncthreads();
    for (int i = tid; i < cnt; i += 256) esrc[base_out + i] = ssrc[i];
}

// ---- f16 helpers ----
__device__ __forceinline__ unsigned pkh2(float a, float b) {
    __half2 h = __floats2half2_rn(a, b);
    return *reinterpret_cast<unsigned*>(&h);
}
__device__ __forceinline__ unsigned hadd2u(unsigned a, unsigned b) {
    __half2 ha = *reinterpret_cast<__half2*>(&a);
    __half2 hb = *reinterpret_cast<__half2*>(&b);
    __half2 r = __hadd2(ha, hb);
    return *reinterpret_cast<unsigned*>(&r);
}
__device__ __forceinline__ float lo2f(unsigned u) { return __low2float(*reinterpret_cast<__half2*>(&u)); }
__device__ __forceinline__ float hi2f(unsigned u) { return __high2float(*reinterpret_cast<__half2*>(&u)); }

// feats f32 -> f16 (RNE), 8 elems/thread
__global__ void f32_to_f16_kernel(const float* __restrict__ in, uint4* __restrict__ out) {
    const int i = blockIdx.x * blockDim.x + threadIdx.x;
    if (i >= N_NODES * D / 8) return;
    const float4* p = reinterpret_cast<const float4*>(in) + (size_t)i * 2;
    const float4 v0 = p[0], v1 = p[1];
    uint4 o;
    o.x = pkh2(v0.x, v0.y); o.y = pkh2(v0.z, v0.w);
    o.z = pkh2(v1.x, v1.y); o.w = pkh2(v1.z, v1.w);
    out[i] = o;
}

#define PK_ADD(g) do { \
    acc01 = hadd2u(acc01, (g).x); acc23 = hadd2u(acc23, (g).y); \
    acc45 = hadd2u(acc45, (g).z); acc67 = hadd2u(acc67, (g).w); } while (0)

// ---- Fused GIN layer, f16 gather + packed-f16 accumulate ----
// Identical structure to the (passing) round-8 kernel: wave = 16 edge-slots
// (es) x 4 feature-quads (fq); one gather covers 16 edges x 64B (a full f16
// row is ONE cache line). Accumulation is v_pk_add_f16 (4 ops/edge/lane =
// same VALU budget as the f32 version), f32 only in the matvec/epilogue.
template <bool RELU, bool POOL>
__global__ void gin_layer_kernel(const uint4* __restrict__ xh,    // f16 rows, 4 uint4/row
                                 const int* __restrict__ esrc,
                                 const int* __restrict__ rend,
                                 const int* __restrict__ deg,
                                 const float* __restrict__ W,
                                 const float* __restrict__ bias,
                                 const int* __restrict__ graph_ids,
                                 float* __restrict__ outf,        // POOL: [128][32] f32
                                 uint2* __restrict__ outh) {      // !POOL: f16 rows, 8 uint2/row
    const int lane = threadIdx.x & 63;
    const int fq = lane & 3;       // feature quad-pair (8 feats)
    const int es = lane >> 2;      // edge slot 0..15
    const int og = lane & 7;       // output quad
    const int ig = lane >> 3;      // input quad

    float w[4][4];
#pragma unroll
    for (int k = 0; k < 4; ++k) {
        const float4 t = *reinterpret_cast<const float4*>(&W[(ig * 4 + k) * D + og * 4]);
        w[k][0] = t.x; w[k][1] = t.y; w[k][2] = t.z; w[k][3] = t.w;
    }
    const float4 bv = *reinterpret_cast<const float4*>(&bias[og * 4]);

    const int wid = blockIdx.x * (blockDim.x >> 6) + (threadIdx.x >> 6);
    const int v0 = wid * NODES_PER_WAVE;
    if (v0 >= N_NODES) return;
    const int v1 = (v0 + NODES_PER_WAVE < N_NODES) ? v0 + NODES_PER_WAVE : N_NODES;

    float p0 = 0.f, p1 = 0.f, p2 = 0.f, p3 = 0.f;
    int cur_g = POOL ? graph_ids[v0] : 0;

    for (int v = v0; v < v1; ++v) {
        const int end = rend[v];
        int e = end - deg[v];

        unsigned acc01 = 0u, acc23 = 0u, acc45 = 0u, acc67 = 0u;   // +0.0h x2 each
        if (es == 0) {   // self term (eps = 0)
            const uint4 sv = xh[(size_t)v * 4 + fq];
            PK_ADD(sv);
        }

        for (; e + 32 <= end; e += 32) {   // 32 edges (2KB) in flight
            const int r0 = esrc[e + es];
            const int r1 = esrc[e + 16 + es];
            const uint4 g0 = xh[(size_t)r0 * 4 + fq];
            const uint4 g1 = xh[(size_t)r1 * 4 + fq];
            PK_ADD(g0); PK_ADD(g1);
        }
        if (e + 16 <= end) {
            const int r0 = esrc[e + es];
            const uint4 g0 = xh[(size_t)r0 * 4 + fq];
            PK_ADD(g0);
            e += 16;
        }
        const int rem = end - e;   // 0..15
        if (es < rem) {
            const int r0 = esrc[e + es];
            const uint4 g0 = xh[(size_t)r0 * 4 + fq];
            PK_ADD(g0);
        }

        // reduce over the 16 es-groups (lane bits 2..5), packed-f16 adds
#pragma unroll
        for (int off = 4; off <= 32; off <<= 1) {
            acc01 = hadd2u(acc01, (unsigned)__shfl_xor((int)acc01, off));
            acc23 = hadd2u(acc23, (unsigned)__shfl_xor((int)acc23, off));
            acc45 = hadd2u(acc45, (unsigned)__shfl_xor((int)acc45, off));
            acc67 = hadd2u(acc67, (unsigned)__shfl_xor((int)acc67, off));
        }

        // fetch input quad ig: full sums live in lane s = ig>>1 (its fq == ig>>1)
        const int s = ig >> 1;
        const int hi = ig & 1;
        const unsigned u0 = (unsigned)__shfl((int)acc01, s);
        const unsigned u1 = (unsigned)__shfl((int)acc23, s);
        const unsigned u2 = (unsigned)__shfl((int)acc45, s);
        const unsigned u3 = (unsigned)__shfl((int)acc67, s);
        const unsigned ua = hi ? u2 : u0;
        const unsigned ub = hi ? u3 : u1;
        const float q0 = lo2f(ua), q1 = hi2f(ua), q2 = lo2f(ub), q3 = hi2f(ub);

        float y0 = q0 * w[0][0] + q1 * w[1][0] + q2 * w[2][0] + q3 * w[3][0];
        float y1 = q0 * w[0][1] + q1 * w[1][1] + q2 * w[2][1] + q3 * w[3][1];
        float y2 = q0 * w[0][2] + q1 * w[1][2] + q2 * w[2][2] + q3 * w[3][2];
        float y3 = q0 * w[0][3] + q1 * w[1][3] + q2 * w[2][3] + q3 * w[3][3];

        // reduce over ig (lane bits 3..5)
#pragma unroll
        for (int off = 8; off <= 32; off <<= 1) {
            y0 += __shfl_xor(y0, off); y1 += __shfl_xor(y1, off);
            y2 += __shfl_xor(y2, off); y3 += __shfl_xor(y3, off);
        }
        y0 += bv.x; y1 += bv.y; y2 += bv.z; y3 += bv.w;
        if (RELU) {
            y0 = fmaxf(y0, 0.f); y1 = fmaxf(y1, 0.f); y2 = fmaxf(y2, 0.f); y3 = fmaxf(y3, 0.f);
        }

        if (POOL) {
            const int g = graph_ids[v];
            if (g != cur_g) {
                if (ig == 0) {
                    atomicAdd(&outf[cur_g * D + og * 4 + 0], p0);
                    atomicAdd(&outf[cur_g * D + og * 4 + 1], p1);
                    atomicAdd(&outf[cur_g * D + og * 4 + 2], p2);
                    atomicAdd(&outf[cur_g * D + og * 4 + 3], p3);
                }
                p0 = p1 = p2 = p3 = 0.f;
                cur_g = g;
            }
            p0 += y0; p1 += y1; p2 += y2; p3 += y3;
        } else if (ig == 0) {
            uint2 o; o.x = pkh2(y0, y1); o.y = pkh2(y2, y3);
            outh[(size_t)v * 8 + og] = o;
        }
    }
    if (POOL && ig == 0) {
        atomicAdd(&outf[cur_g * D + og * 4 + 0], p0);
        atomicAdd(&outf[cur_g * D + og * 4 + 1], p1);
        atomicAdd(&outf[cur_g * D + og * 4 + 2], p2);
        atomicAdd(&outf[cur_g * D + og * 4 + 3], p3);
    }
}

extern "C" void kernel_launch(void* const* d_in, const int* in_sizes, int n_in,
                              void* d_out, int out_size, void* d_ws, size_t ws_size,
                              hipStream_t stream) {
    const float* feats = (const float*)d_in[0];
    const int* src = (const int*)d_in[1];
    const int* dst = (const int*)d_in[2];
    const int* graph_ids = (const int*)d_in[3];
    const float* W1 = (const float*)d_in[4];
    const float* b1 = (const float*)d_in[5];
    const float* W2 = (const float*)d_in[6];
    const float* b2 = (const float*)d_in[7];
    float* out = (float*)d_out;

    int* gfill = (int*)d_ws;                               // 1024
    int* wbase = gfill + 1024;                             // 1024 (NWINS+1)
    int* ebuf  = wbase + 1024;                             // NWINS*CAP (~8 MB)
    int* esrc  = ebuf + (size_t)NWINS * CAP;               // N_EDGES
    int* rend  = esrc + N_EDGES;                           // N_NODES
    int* deg   = rend + N_NODES;                           // N_NODES
    unsigned* xh = (unsigned*)(deg + N_NODES);             // N_NODES*16 uints (f16 feats)
    unsigned* hh = xh + (size_t)N_NODES * (D / 2);         // N_NODES*16 uints (f16 h)

    const int total_waves = (N_NODES + NODES_PER_WAVE - 1) / NODES_PER_WAVE;  // 12500
    const int layer_blocks = (total_waves + 3) / 4;

    // ---- Build dst-sorted CSR via window binning + LDS-local sort ----
    hipMemsetAsync(gfill, 0, 1024 * sizeof(int), stream);
    bin_kernel<<<256, 512, 0, stream>>>(src, dst, gfill, ebuf);
    wscan_kernel<<<1, 1024, 0, stream>>>(gfill, wbase);
    csr_local_kernel<<<NWINS, 256, 0, stream>>>(ebuf, wbase, esrc, rend, deg);

    // ---- feats -> f16 ----
    f32_to_f16_kernel<<<(N_NODES * D / 8 + 255) / 256, 256, 0, stream>>>(
        feats, (uint4*)xh);

    // ---- Layer 1: hh = f16(relu((x + agg(x)) @ W1 + b1)) ----
    gin_layer_kernel<true, false><<<layer_blocks, 256, 0, stream>>>(
        (const uint4*)xh, esrc, rend, deg, W1, b1, graph_ids, nullptr, (uint2*)hh);

    // ---- Layer 2 + sum pooling (f32 out) ----
    hipMemsetAsync(out, 0, (size_t)out_size * sizeof(float), stream);
    gin_layer_kernel<false, true><<<layer_blocks, 256, 0, stream>>>(
        (const uint4*)hh, esrc, rend, deg, W2, b2, graph_ids, out, nullptr);
}